// Round 12
// baseline (71.680 us; speedup 1.0000x reference)
//
#include <hip/hip_runtime.h>
#include <math.h>

// PatchNorm forward (training-mode Welford update + normalize), 3 kernels.
// Rounds 6-11 lesson: the fused per-cell kernel is scatter-bound on BOTH
// sides (87MB scattered 3KB-row reads + 98MB scattered 3KB-row writes),
// pinned at ~2.7 TB/s regardless of MLP/TLP heroics. Only xbar (1KB/row,
// 32MB total) actually needs cell-gathering. So:
//   k_prep:  STREAM patches (96MB seq read) -> xbar (32MB seq write) + pf16
//   k_stats: per-cell scan of pf16 + gather of 1KB xbar rows (L3-hot)
//            -> closed-form stats -> mean_new/inv_std (2MB)
//   k_norm:  STREAM patches (L3-hot seq read) + stats gather (2MB L2)
//            -> out (96MB seq write); pads zeroed via wv=0
//
// Closed-form per-cell moments (n_g uniform within a cell):
//   mean_new = mo + (S1 - cnt*mo)/n_g                 S1 = sum_valid xbar
//   m2_new   = m2 + S2 - (mo+mn)*S1 + cnt*mo*mn       S2 = sum_valid xbar^2

#define EPSF 1e-6f

static constexpr int W_GRID  = 32;    // grid width (pf = pos_h*W + pos_w)
static constexpr int P2      = 256;   // patch_res^2
static constexpr int P4      = 64;    // P2/4
static constexpr int D4      = 192;   // D/4 float4 chunks per token
static constexpr int HW      = 1024;  // grid cells
static constexpr int NTOK    = 32768; // tokens
static constexpr int LISTCAP = 96;    // token-list capacity (E[cnt]=28.8, max~50)
static constexpr int CPB     = 1536;  // float4 chunks per k_norm block (8 tokens)

// ---- kernel 1: streaming prep: pf16 + xbar ---------------------------------
// Block = 4 waves = 4 consecutive tokens. Lane l reads the token row's float4
// chunks l, l+64, l+128 (three coalesced 1KB segments), writes xbar4 chunk l.
__global__ void __launch_bounds__(256)
k_prep(const float4* __restrict__ patches4,
       const int* __restrict__ pos_h,
       const int* __restrict__ pos_w,
       const int* __restrict__ mask,
       unsigned short* __restrict__ pf16,
       float4* __restrict__ xbar4,
       int do_xbar) {
    const int tid  = threadIdx.x;
    const int wave = tid >> 6;
    const int lane = tid & 63;
    const int i    = blockIdx.x * 4 + wave;       // token

    if (lane == 0) {
        const int valid = (mask[i] == 0);
        pf16[i] = valid ? (unsigned short)(pos_h[i] * W_GRID + pos_w[i])
                        : (unsigned short)0xFFFF;
    }
    if (do_xbar) {
        const float4* tp = patches4 + (size_t)i * D4 + lane;
        const float4 a = tp[0];
        const float4 b = tp[P4];
        const float4 d = tp[2 * P4];
        float4 xb;
        xb.x = (a.x + b.x + d.x) * (1.0f / 3.0f);
        xb.y = (a.y + b.y + d.y) * (1.0f / 3.0f);
        xb.z = (a.z + b.z + d.z) * (1.0f / 3.0f);
        xb.w = (a.w + b.w + d.w) * (1.0f / 3.0f);
        xbar4[(size_t)i * P4 + lane] = xb;
    }
}

// ---- kernel 2: per-cell scan + xbar gather + fused stats -------------------
__global__ void __launch_bounds__(256)
k_stats(const float4* __restrict__ patches4,
        const float4* __restrict__ xbar4,
        const unsigned short* __restrict__ pf16,
        const float* __restrict__ n_old,
        const float* __restrict__ mean_old,
        const float* __restrict__ m2_old,
        float* __restrict__ mean_new,
        float* __restrict__ inv_std,
        int use_xbar) {
    const int g    = blockIdx.x;
    const int tid  = threadIdx.x;
    const int wave = tid >> 6;
    const int lane = tid & 63;

    __shared__ int    list[LISTCAP];
    __shared__ int    s_cnt;
    __shared__ float4 l14[4][64];
    __shared__ float4 l24[4][64];

    if (tid == 0) s_cnt = 0;

    // preload the whole pf16 scan (16 int4 loads in flight; L2-broadcast)
    const int4* pp = (const int4*)pf16;
    int4 v[16];
#pragma unroll
    for (int it = 0; it < 16; ++it) v[it] = pp[it * 256 + tid];
    __syncthreads();

#pragma unroll
    for (int it = 0; it < 16; ++it) {
        const int base = (it * 256 + tid) * 8;
#pragma unroll
        for (int k = 0; k < 4; ++k) {
            const int word = (&v[it].x)[k];
            const int g0 = word & 0xFFFF;
            const int g1 = (word >> 16) & 0xFFFF;
            if (g0 == g) { int s = atomicAdd(&s_cnt, 1); if (s < LISTCAP) list[s] = base + 2 * k; }
            if (g1 == g) { int s = atomicAdd(&s_cnt, 1); if (s < LISTCAP) list[s] = base + 2 * k + 1; }
        }
    }
    __syncthreads();
    const int c = min(s_cnt, LISTCAP);

    float4 s1 = make_float4(0.f, 0.f, 0.f, 0.f);
    float4 s2 = make_float4(0.f, 0.f, 0.f, 0.f);

    if (use_xbar) {
        // gather 1KB xbar rows (L3-hot), 4-deep predicated batches
        for (int k = wave; k < c; k += 16) {
            int   idx[4];
            float wf[4];
#pragma unroll
            for (int j = 0; j < 4; ++j) {
                const int  kk  = k + 4 * j;
                const bool val = (kk < c);
                wf[j]  = val ? 1.0f : 0.0f;
                idx[j] = list[val ? kk : k];
            }
            float4 X[4];
#pragma unroll
            for (int j = 0; j < 4; ++j)
                X[j] = xbar4[(size_t)idx[j] * P4 + lane];
#pragma unroll
            for (int j = 0; j < 4; ++j) {
                float4 xb;
                xb.x = X[j].x * wf[j];  xb.y = X[j].y * wf[j];
                xb.z = X[j].z * wf[j];  xb.w = X[j].w * wf[j];
                s1.x += xb.x; s1.y += xb.y; s1.z += xb.z; s1.w += xb.w;
                s2.x += xb.x * xb.x; s2.y += xb.y * xb.y;
                s2.z += xb.z * xb.z; s2.w += xb.w * xb.w;
            }
        }
    } else {
        // fallback (small workspace): gather 3KB patch rows directly
        for (int k = wave; k < c; k += 16) {
            int   idx[4];
            float wf[4];
#pragma unroll
            for (int j = 0; j < 4; ++j) {
                const int  kk  = k + 4 * j;
                const bool val = (kk < c);
                wf[j]  = val ? 1.0f : 0.0f;
                idx[j] = list[val ? kk : k];
            }
            float4 A[4], B[4], Dd[4];
#pragma unroll
            for (int j = 0; j < 4; ++j) {
                const float4* tp = patches4 + (size_t)idx[j] * D4 + lane;
                A[j]  = tp[0];
                B[j]  = tp[P4];
                Dd[j] = tp[2 * P4];
            }
#pragma unroll
            for (int j = 0; j < 4; ++j) {
                const float f = (1.0f / 3.0f) * wf[j];
                float4 xb;
                xb.x = (A[j].x + B[j].x + Dd[j].x) * f;
                xb.y = (A[j].y + B[j].y + Dd[j].y) * f;
                xb.z = (A[j].z + B[j].z + Dd[j].z) * f;
                xb.w = (A[j].w + B[j].w + Dd[j].w) * f;
                s1.x += xb.x; s1.y += xb.y; s1.z += xb.z; s1.w += xb.w;
                s2.x += xb.x * xb.x; s2.y += xb.y * xb.y;
                s2.z += xb.z * xb.z; s2.w += xb.w * xb.w;
            }
        }
    }

    // cross-wave reduce + closed-form stats (tid = p index)
    l14[wave][lane] = s1;
    l24[wave][lane] = s2;
    __syncthreads();

    const float* l1f = (const float*)l14;
    const float* l2f = (const float*)l24;
    const float S1 = l1f[tid] + l1f[256 + tid] + l1f[512 + tid] + l1f[768 + tid];
    const float S2 = l2f[tid] + l2f[256 + tid] + l2f[512 + tid] + l2f[768 + tid];

    const float cnt = (float)c;
    const float nn  = n_old[g] + cnt;
    const float ng  = fmaxf(nn, 1.0f);
    const int   j   = g * P2 + tid;
    const float mo  = mean_old[j];
    const float mn  = mo + (S1 - cnt * mo) / ng;
    const float m2n = m2_old[j] + (S2 - (mo + mn) * S1 + cnt * mo * mn);
    const float var = (nn < 2.0f) ? 1.0f : (m2n / ng);
    mean_new[j] = mn;
    inv_std[j]  = 1.0f / (sqrtf(var) + EPSF);
}

// ---- kernel 3: sequential normalize ----------------------------------------
// 4096 blocks x 256 threads; block b owns chunks [b*1536,(b+1)*1536) = tokens
// [8b, 8b+8). Sequential read (L3-hot) + sequential write; pads via wv=0.
__global__ void __launch_bounds__(256)
k_norm(const float4* __restrict__ patches4,
       const unsigned short* __restrict__ pf16,
       const float4* __restrict__ mn4,
       const float4* __restrict__ is4,
       float4* __restrict__ out4) {
    const int b     = blockIdx.x;
    const int tid   = threadIdx.x;
    const int cbase = b * CPB;
    const int tok0  = b * 8;

    __shared__ unsigned short s_gg[8];
    if (tid < 8) s_gg[tid] = pf16[tok0 + tid];

    // issue all 6 patch loads up front (sequential, coalesced)
    float4 x[6];
#pragma unroll
    for (int j = 0; j < 6; ++j) x[j] = patches4[cbase + j * 256 + tid];
    __syncthreads();

    int   gx[6], pidx[6];
    float wv[6];
#pragma unroll
    for (int j = 0; j < 6; ++j) {
        const int local = j * 256 + tid;      // 0..1535
        const int lt    = local / 192;        // local token 0..7 (const-div)
        pidx[j] = (local - lt * 192) & 63;    // p4 within cell row
        const unsigned short gg = s_gg[lt];
        wv[j] = (gg != 0xFFFF) ? 1.0f : 0.0f;
        gx[j] = (gg != 0xFFFF) ? (int)gg : 0;
    }

    float4 m[6], s[6];
#pragma unroll
    for (int j = 0; j < 6; ++j) {
        m[j] = mn4[gx[j] * P4 + pidx[j]];
        s[j] = is4[gx[j] * P4 + pidx[j]];
    }
#pragma unroll
    for (int j = 0; j < 6; ++j) {
        float4 o;
        o.x = (x[j].x - m[j].x) * s[j].x * wv[j];
        o.y = (x[j].y - m[j].y) * s[j].y * wv[j];
        o.z = (x[j].z - m[j].z) * s[j].z * wv[j];
        o.w = (x[j].w - m[j].w) * s[j].w * wv[j];
        out4[cbase + j * 256 + tid] = o;
    }
}

extern "C" void kernel_launch(void* const* d_in, const int* in_sizes, int n_in,
                              void* d_out, int out_size, void* d_ws, size_t ws_size,
                              hipStream_t stream) {
    const float4* patches4 = (const float4*)d_in[0];
    const int*    pos_h    = (const int*)d_in[1];
    const int*    pos_w    = (const int*)d_in[2];
    const int*    mask     = (const int*)d_in[3];
    const float*  n_old    = (const float*)d_in[4];
    const float*  mean     = (const float*)d_in[5];
    const float*  m2       = (const float*)d_in[6];
    float4* out4 = (float4*)d_out;

    // workspace: ushort pf16[NTOK] | f32 mean_new[HW*P2] | f32 inv_std[HW*P2]
    //            | f32 xbar[NTOK*P2] (32MB, optional)
    unsigned short* pf16 = (unsigned short*)d_ws;
    float* mean_new = (float*)(pf16 + NTOK);
    float* inv_std  = mean_new + (size_t)HW * P2;
    float* xbar     = inv_std + (size_t)HW * P2;

    const size_t need = (size_t)NTOK * 2 + (size_t)2 * HW * P2 * 4
                      + (size_t)NTOK * P2 * 4;
    const int use_xbar = (ws_size >= need) ? 1 : 0;

    k_prep<<<NTOK / 4, 256, 0, stream>>>(patches4, pos_h, pos_w, mask,
                                         pf16, (float4*)xbar, use_xbar);
    k_stats<<<HW, 256, 0, stream>>>(patches4, (const float4*)xbar, pf16,
                                    n_old, mean, m2, mean_new, inv_std, use_xbar);
    k_norm<<<(NTOK * D4) / CPB, 256, 0, stream>>>(patches4, pf16,
                                                  (const float4*)mean_new,
                                                  (const float4*)inv_std, out4);
}

// Round 13
// 68.421 us; speedup vs baseline: 1.0476x; 1.0476x over previous
//
#include <hip/hip_runtime.h>
#include <math.h>

// PatchNorm forward (training-mode Welford update + normalize), 3 kernels,
// ALL heavy phases sequential:
//   k_prep:  stream patches (96MB seq read) -> xbar in BF16 (16MB seq write,
//            stashed in d_out's first 16.8MB) + pf16 cell ids
//   k_stats: per-cell scan of pf16 + gather of 512B bf16 xbar rows (L3-hot,
//            ~15MB total) -> closed-form stats -> mean_new/inv_std (2MB, ws)
//   k_norm:  stream patches (L3-hot seq read) + out (96MB seq write); stats
//            rows for the block's 8 tokens staged in LDS (kills the scattered
//            per-thread stat lookups that plagued R8/R12); pads via wv=0.
// d_out reuse is safe: k_stats consumes xbarh before k_norm overwrites out
// (stream-ordered), and k_norm rewrites every out element each call.
//
// Closed-form per-cell moments (n_g uniform within a cell):
//   mean_new = mo + (S1 - cnt*mo)/n_g                 S1 = sum_valid xbar
//   m2_new   = m2 + S2 - (mo+mn)*S1 + cnt*mo*mn       S2 = sum_valid xbar^2

#define EPSF 1e-6f

static constexpr int W_GRID  = 32;    // grid width (pf = pos_h*W + pos_w)
static constexpr int P2      = 256;   // patch_res^2
static constexpr int P4      = 64;    // P2/4
static constexpr int D4      = 192;   // D/4 float4 chunks per token
static constexpr int HW      = 1024;  // grid cells
static constexpr int NTOK    = 32768; // tokens
static constexpr int LISTCAP = 96;    // token-list capacity (E[cnt]=28.8, max~50)
static constexpr int CPB     = 1536;  // float4 chunks per k_norm block (8 tokens)

__device__ __forceinline__ unsigned short f2bf(float f) {   // RNE f32->bf16
    unsigned int u = __float_as_uint(f);
    u += 0x7FFFu + ((u >> 16) & 1u);
    return (unsigned short)(u >> 16);
}
__device__ __forceinline__ float bf2f(unsigned short h) {
    return __uint_as_float(((unsigned int)h) << 16);
}

// ---- kernel 1: streaming prep: pf16 + bf16 xbar ----------------------------
// Block = 4 waves = 4 consecutive tokens. Lane l reads float4 chunks l, l+64,
// l+128 (three coalesced 1KB segments), writes one ushort4 (8B) of xbarh.
__global__ void __launch_bounds__(256)
k_prep(const float4* __restrict__ patches4,
       const int* __restrict__ pos_h,
       const int* __restrict__ pos_w,
       const int* __restrict__ mask,
       unsigned short* __restrict__ pf16,
       ushort4* __restrict__ xbarh) {
    const int tid  = threadIdx.x;
    const int wave = tid >> 6;
    const int lane = tid & 63;
    const int i    = blockIdx.x * 4 + wave;       // token

    if (lane == 0) {
        const int valid = (mask[i] == 0);
        pf16[i] = valid ? (unsigned short)(pos_h[i] * W_GRID + pos_w[i])
                        : (unsigned short)0xFFFF;
    }
    const float4* tp = patches4 + (size_t)i * D4 + lane;
    const float4 a = tp[0];
    const float4 b = tp[P4];
    const float4 d = tp[2 * P4];
    ushort4 h;
    h.x = f2bf((a.x + b.x + d.x) * (1.0f / 3.0f));
    h.y = f2bf((a.y + b.y + d.y) * (1.0f / 3.0f));
    h.z = f2bf((a.z + b.z + d.z) * (1.0f / 3.0f));
    h.w = f2bf((a.w + b.w + d.w) * (1.0f / 3.0f));
    xbarh[(size_t)i * P4 + lane] = h;
}

// ---- kernel 2: per-cell scan + bf16 xbar gather + fused stats --------------
__global__ void __launch_bounds__(256)
k_stats(const ushort4* __restrict__ xbarh,
        const unsigned short* __restrict__ pf16,
        const float* __restrict__ n_old,
        const float* __restrict__ mean_old,
        const float* __restrict__ m2_old,
        float* __restrict__ mean_new,
        float* __restrict__ inv_std) {
    const int g    = blockIdx.x;
    const int tid  = threadIdx.x;
    const int wave = tid >> 6;
    const int lane = tid & 63;

    __shared__ int    list[LISTCAP];
    __shared__ int    s_cnt;
    __shared__ float4 l14[4][64];
    __shared__ float4 l24[4][64];

    if (tid == 0) s_cnt = 0;

    // preload the whole pf16 scan (16 int4 loads in flight; L2-broadcast)
    const int4* pp = (const int4*)pf16;
    int4 v[16];
#pragma unroll
    for (int it = 0; it < 16; ++it) v[it] = pp[it * 256 + tid];
    __syncthreads();

#pragma unroll
    for (int it = 0; it < 16; ++it) {
        const int base = (it * 256 + tid) * 8;
#pragma unroll
        for (int k = 0; k < 4; ++k) {
            const int word = (&v[it].x)[k];
            const int g0 = word & 0xFFFF;
            const int g1 = (word >> 16) & 0xFFFF;
            if (g0 == g) { int s = atomicAdd(&s_cnt, 1); if (s < LISTCAP) list[s] = base + 2 * k; }
            if (g1 == g) { int s = atomicAdd(&s_cnt, 1); if (s < LISTCAP) list[s] = base + 2 * k + 1; }
        }
    }
    __syncthreads();
    const int c = min(s_cnt, LISTCAP);

    // gather 512B bf16 xbar rows (just written -> L2/L3-hot), 4-deep batches
    float4 s1 = make_float4(0.f, 0.f, 0.f, 0.f);
    float4 s2 = make_float4(0.f, 0.f, 0.f, 0.f);
    for (int k = wave; k < c; k += 16) {
        int   idx[4];
        float wf[4];
#pragma unroll
        for (int j = 0; j < 4; ++j) {
            const int  kk  = k + 4 * j;
            const bool val = (kk < c);
            wf[j]  = val ? 1.0f : 0.0f;
            idx[j] = list[val ? kk : k];      // k itself is always < c
        }
        ushort4 X[4];
#pragma unroll
        for (int j = 0; j < 4; ++j)
            X[j] = xbarh[(size_t)idx[j] * P4 + lane];
#pragma unroll
        for (int j = 0; j < 4; ++j) {
            float4 xb;
            xb.x = bf2f(X[j].x) * wf[j];
            xb.y = bf2f(X[j].y) * wf[j];
            xb.z = bf2f(X[j].z) * wf[j];
            xb.w = bf2f(X[j].w) * wf[j];
            s1.x += xb.x; s1.y += xb.y; s1.z += xb.z; s1.w += xb.w;
            s2.x += xb.x * xb.x; s2.y += xb.y * xb.y;
            s2.z += xb.z * xb.z; s2.w += xb.w * xb.w;
        }
    }

    // cross-wave reduce + closed-form stats (tid = p index)
    l14[wave][lane] = s1;
    l24[wave][lane] = s2;
    __syncthreads();

    const float* l1f = (const float*)l14;
    const float* l2f = (const float*)l24;
    const float S1 = l1f[tid] + l1f[256 + tid] + l1f[512 + tid] + l1f[768 + tid];
    const float S2 = l2f[tid] + l2f[256 + tid] + l2f[512 + tid] + l2f[768 + tid];

    const float cnt = (float)c;
    const float nn  = n_old[g] + cnt;
    const float ng  = fmaxf(nn, 1.0f);
    const int   j   = g * P2 + tid;
    const float mo  = mean_old[j];
    const float mn  = mo + (S1 - cnt * mo) / ng;
    const float m2n = m2_old[j] + (S2 - (mo + mn) * S1 + cnt * mo * mn);
    const float var = (nn < 2.0f) ? 1.0f : (m2n / ng);
    mean_new[j] = mn;
    inv_std[j]  = 1.0f / (sqrtf(var) + EPSF);
}

// ---- kernel 3: sequential normalize with LDS-staged stats ------------------
// 4096 blocks x 256 threads; block b owns chunks [b*1536,(b+1)*1536) = tokens
// [8b, 8b+8). Stats rows for the 8 tokens staged in LDS (16KB) -- one
// coalesced 1KB row load per table per cell instead of 12 scattered 16B
// lookups per thread. Sequential read + sequential write; pads via wv=0.
__global__ void __launch_bounds__(256)
k_norm(const float4* __restrict__ patches4,
       const unsigned short* __restrict__ pf16,
       const float4* __restrict__ mn4,
       const float4* __restrict__ is4,
       float4* __restrict__ out4) {
    const int b     = blockIdx.x;
    const int tid   = threadIdx.x;
    const int cbase = b * CPB;
    const int tok0  = b * 8;

    __shared__ unsigned short s_gg[8];
    __shared__ float4 mn_s[8][64];
    __shared__ float4 is_s[8][64];

    // issue all 6 patch loads up front (sequential, coalesced)
    float4 x[6];
#pragma unroll
    for (int j = 0; j < 6; ++j) x[j] = patches4[cbase + j * 256 + tid];

    if (tid < 8) s_gg[tid] = pf16[tok0 + tid];
    __syncthreads();

    // stage stats rows: slot r = tid>>5, quarter q0 = tid&31 (2 float4s each)
    {
        const int r  = tid >> 5;
        const int q0 = tid & 31;
        const unsigned short gg = s_gg[r];
        const int gx = (gg != 0xFFFF) ? (int)gg : 0;
        mn_s[r][q0]      = mn4[gx * P4 + q0];
        mn_s[r][q0 + 32] = mn4[gx * P4 + q0 + 32];
        is_s[r][q0]      = is4[gx * P4 + q0];
        is_s[r][q0 + 32] = is4[gx * P4 + q0 + 32];
    }
    __syncthreads();

#pragma unroll
    for (int j = 0; j < 6; ++j) {
        const int local = j * 256 + tid;      // 0..1535
        const int lt    = local / 192;        // local token 0..7 (const-div)
        const int pp    = local & 63;         // p4 within cell row
        const float wv  = (s_gg[lt] != 0xFFFF) ? 1.0f : 0.0f;
        const float4 m  = mn_s[lt][pp];
        const float4 s  = is_s[lt][pp];
        float4 o;
        o.x = (x[j].x - m.x) * s.x * wv;
        o.y = (x[j].y - m.y) * s.y * wv;
        o.z = (x[j].z - m.z) * s.z * wv;
        o.w = (x[j].w - m.w) * s.w * wv;
        out4[cbase + j * 256 + tid] = o;
    }
}

extern "C" void kernel_launch(void* const* d_in, const int* in_sizes, int n_in,
                              void* d_out, int out_size, void* d_ws, size_t ws_size,
                              hipStream_t stream) {
    const float4* patches4 = (const float4*)d_in[0];
    const int*    pos_h    = (const int*)d_in[1];
    const int*    pos_w    = (const int*)d_in[2];
    const int*    mask     = (const int*)d_in[3];
    const float*  n_old    = (const float*)d_in[4];
    const float*  mean     = (const float*)d_in[5];
    const float*  m2       = (const float*)d_in[6];
    float4* out4 = (float4*)d_out;

    // bf16 xbar lives in d_out's first 16.8MB (consumed before k_norm writes)
    ushort4* xbarh = (ushort4*)d_out;

    // workspace: ushort pf16[NTOK] (64KB) | f32 mean_new[1MB] | inv_std[1MB]
    unsigned short* pf16 = (unsigned short*)d_ws;
    float* mean_new = (float*)(pf16 + NTOK);
    float* inv_std  = mean_new + (size_t)HW * P2;

    k_prep<<<NTOK / 4, 256, 0, stream>>>(patches4, pos_h, pos_w, mask,
                                         pf16, xbarh);
    k_stats<<<HW, 256, 0, stream>>>((const ushort4*)xbarh, pf16,
                                    n_old, mean, m2, mean_new, inv_std);
    k_norm<<<(NTOK * D4) / CPB, 256, 0, stream>>>(patches4, pf16,
                                                  (const float4*)mean_new,
                                                  (const float4*)inv_std, out4);
}

// Round 14
// 57.082 us; speedup vs baseline: 1.2557x; 1.1986x over previous
//
#include <hip/hip_runtime.h>
#include <math.h>

// PatchNorm forward (training-mode Welford update + normalize), 2 kernels:
//   k_pf:   pack per-token cell id into ushort (0xFFFF = padded)
//   k_cell: one block per grid cell -- scan pf16 -> token list in LDS ->
//           gather rows (predicated 4-deep batches, NORMAL loads: seed L3) ->
//           closed-form stats in LDS -> normalize the SAME rows with
//           NON-TEMPORAL re-read loads + NON-TEMPORAL output stores.
// Round-13 lesson: split pipelines lose 6-10us to extra passes; fused wins.
// Round-14 theory: per XCD, 128 blocks x ~120KB gathered rows = 15MB live
// footprint vs 4MB L2 -> re-read is L3-served while gather-allocs + 98MB of
// store-allocs thrash L2. NT hints remove the useless L2 allocation.
//
// Closed-form per-cell moments (n_g uniform within a cell):
//   mean_new = mo + (S1 - cnt*mo)/n_g                 S1 = sum_valid xbar
//   m2_new   = m2 + S2 - (mo+mn)*S1 + cnt*mo*mn       S2 = sum_valid xbar^2

#define EPSF 1e-6f

typedef float v4 __attribute__((ext_vector_type(4)));

static constexpr int W_GRID  = 32;    // grid width (pf = pos_h*W + pos_w)
static constexpr int P2      = 256;   // patch_res^2
static constexpr int P4      = 64;    // P2/4
static constexpr int D4      = 192;   // D/4 v4 chunks per token
static constexpr int HW      = 1024;  // grid cells
static constexpr int NTOK    = 32768; // tokens
static constexpr int LISTCAP = 96;    // token-list capacity (E[cnt]=28.8, max~50)
static constexpr int SLICE   = NTOK / HW; // 32 tokens/block for pad-zeroing

// ---- kernel 1: pack per-token cell id (0xFFFF = padded) --------------------
__global__ void k_pf(const int* __restrict__ pos_h,
                     const int* __restrict__ pos_w,
                     const int* __restrict__ mask,
                     unsigned short* __restrict__ pf16) {
    int i = blockIdx.x * blockDim.x + threadIdx.x;
    if (i >= NTOK) return;
    const int valid = (mask[i] == 0);
    pf16[i] = valid ? (unsigned short)(pos_h[i] * W_GRID + pos_w[i])
                    : (unsigned short)0xFFFF;
}

// ---- kernel 2: fused per-cell moments + stats + normalize ------------------
__global__ void __launch_bounds__(256, 4)
k_cell(const v4* __restrict__ patches4,
       const unsigned short* __restrict__ pf16,
       const float* __restrict__ n_old,
       const float* __restrict__ mean_old,
       const float* __restrict__ m2_old,
       v4* __restrict__ out4) {
    const int g    = blockIdx.x;
    const int tid  = threadIdx.x;
    const int wave = tid >> 6;
    const int lane = tid & 63;

    __shared__ int            list[LISTCAP];
    __shared__ int            s_cnt;
    __shared__ unsigned short s_slice[SLICE];
    __shared__ v4             l14[4][64];
    __shared__ v4             l24[4][64];
    __shared__ v4             mn_s[P4];
    __shared__ v4             is_s[P4];

    if (tid == 0) s_cnt = 0;
    if (tid < SLICE) s_slice[tid] = pf16[g * SLICE + tid];

    // ---- issue ALL scan loads up front (16 independent L2 loads) -----------
    const int4* pp = (const int4*)pf16;
    int4 v[16];
#pragma unroll
    for (int it = 0; it < 16; ++it) v[it] = pp[it * 256 + tid];

    __syncthreads();

    // ---- pad-zeroing for this block's 32-token slice (NT stores) -----------
    const v4 zero4 = {0.f, 0.f, 0.f, 0.f};
#pragma unroll
    for (int t = 0; t < SLICE; ++t) {
        if (s_slice[t] == 0xFFFF) {
            const int i = g * SLICE + t;
            if (tid < D4)
                __builtin_nontemporal_store(zero4, out4 + (size_t)i * D4 + tid);
        }
    }

    // ---- process scan chunks -> LDS token list -----------------------------
#pragma unroll
    for (int it = 0; it < 16; ++it) {
        const int base = (it * 256 + tid) * 8;
#pragma unroll
        for (int k = 0; k < 4; ++k) {
            const int word = (&v[it].x)[k];
            const int g0 = word & 0xFFFF;
            const int g1 = (word >> 16) & 0xFFFF;
            if (g0 == g) { int s = atomicAdd(&s_cnt, 1); if (s < LISTCAP) list[s] = base + 2 * k; }
            if (g1 == g) { int s = atomicAdd(&s_cnt, 1); if (s < LISTCAP) list[s] = base + 2 * k + 1; }
        }
    }
    __syncthreads();
    const int c = min(s_cnt, LISTCAP);

    // ---- gather: S1/S2 moments, predicated 4-deep batches (normal loads) ---
    v4 s1 = zero4;
    v4 s2 = zero4;
    for (int k = wave; k < c; k += 16) {
        int   idx[4];
        float wf[4];
#pragma unroll
        for (int j = 0; j < 4; ++j) {
            const int  kk  = k + 4 * j;
            const bool val = (kk < c);
            wf[j]  = val ? 1.0f : 0.0f;
            idx[j] = list[val ? kk : k];      // k itself is always < c
        }
        v4 A[4], B[4], Dd[4];
#pragma unroll
        for (int j = 0; j < 4; ++j) {
            const v4* tp = patches4 + (size_t)idx[j] * D4 + lane;
            A[j]  = tp[0];
            B[j]  = tp[P4];
            Dd[j] = tp[2 * P4];
        }
#pragma unroll
        for (int j = 0; j < 4; ++j) {
            const v4 xb = (A[j] + B[j] + Dd[j]) * ((1.0f / 3.0f) * wf[j]);
            s1 += xb;
            s2 += xb * xb;                     // wf^2 == wf
        }
    }

    // ---- cross-wave reduce + closed-form stats (tid = p index) -------------
    l14[wave][lane] = s1;
    l24[wave][lane] = s2;
    __syncthreads();

    {
        const float* l1f = (const float*)l14;
        const float* l2f = (const float*)l24;
        const float S1 = l1f[tid] + l1f[256 + tid] + l1f[512 + tid] + l1f[768 + tid];
        const float S2 = l2f[tid] + l2f[256 + tid] + l2f[512 + tid] + l2f[768 + tid];

        const float cnt = (float)c;
        const float nn  = n_old[g] + cnt;
        const float ng  = fmaxf(nn, 1.0f);
        const int   j   = g * P2 + tid;
        const float mo  = mean_old[j];
        const float mn  = mo + (S1 - cnt * mo) / ng;
        const float m2n = m2_old[j] + (S2 - (mo + mn) * S1 + cnt * mo * mn);
        const float var = (nn < 2.0f) ? 1.0f : (m2n / ng);
        ((float*)mn_s)[tid] = mn;
        ((float*)is_s)[tid] = 1.0f / (sqrtf(var) + EPSF);
    }
    __syncthreads();

    // ---- normalize the same rows: NT re-read + NT stores -------------------
    const v4 m4 = mn_s[lane];
    const v4 s4 = is_s[lane];
    for (int k = wave; k < c; k += 16) {
        int  idx[4];
        bool val[4];
#pragma unroll
        for (int j = 0; j < 4; ++j) {
            const int kk = k + 4 * j;
            val[j] = (kk < c);                // wave-uniform predicate
            idx[j] = list[val[j] ? kk : k];
        }
        v4 X[12];
#pragma unroll
        for (int j = 0; j < 4; ++j) {
            const v4* tp = patches4 + (size_t)idx[j] * D4 + lane;
            X[3 * j]     = __builtin_nontemporal_load(tp);
            X[3 * j + 1] = __builtin_nontemporal_load(tp + P4);
            X[3 * j + 2] = __builtin_nontemporal_load(tp + 2 * P4);
        }
#pragma unroll
        for (int j = 0; j < 4; ++j) {
            if (val[j]) {                     // uniform branch: masked stores
                v4* op = out4 + (size_t)idx[j] * D4 + lane;
                __builtin_nontemporal_store((X[3 * j]     - m4) * s4, op);
                __builtin_nontemporal_store((X[3 * j + 1] - m4) * s4, op + P4);
                __builtin_nontemporal_store((X[3 * j + 2] - m4) * s4, op + 2 * P4);
            }
        }
    }
}

extern "C" void kernel_launch(void* const* d_in, const int* in_sizes, int n_in,
                              void* d_out, int out_size, void* d_ws, size_t ws_size,
                              hipStream_t stream) {
    const v4*  patches4 = (const v4*)d_in[0];
    const int* pos_h    = (const int*)d_in[1];
    const int* pos_w    = (const int*)d_in[2];
    const int* mask     = (const int*)d_in[3];
    const float* n_old  = (const float*)d_in[4];
    const float* mean   = (const float*)d_in[5];
    const float* m2     = (const float*)d_in[6];
    v4* out4 = (v4*)d_out;

    // workspace: ushort pf16[NTOK] (64 KB)
    unsigned short* pf16 = (unsigned short*)d_ws;

    k_pf<<<NTOK / 256, 256, 0, stream>>>(pos_h, pos_w, mask, pf16);
    k_cell<<<HW, 256, 0, stream>>>(patches4, pf16, n_old, mean, m2, out4);
}